// Round 11
// baseline (811.839 us; speedup 1.0000x reference)
//
#include <hip/hip_runtime.h>
#include <hip/hip_fp16.h>

typedef _Float16 h2v __attribute__((ext_vector_type(2)));
typedef _Float16 f16x8 __attribute__((ext_vector_type(8)));
typedef float f32x4 __attribute__((ext_vector_type(4)));
typedef unsigned int u32;
typedef unsigned short u16;

#define NB 256
#define NP 512
#define NH 256

// ws layout in dwords
// WH: Wh B-frags. dword F = (((w*48 + f)*64 + l)*4 + d)
//   f = t*8 + kt; t = g*2 + c (g=gate 0..2, c=col-half 0..1), kt = K-tile 0..7
//   k = kt*32 + (l>>4)*8 + 2d (+1 for hi half), col = g*256 + w*32 + c*16 + (l&15)
#define OFF_WH 0
#define LEN_WH 98304            // 8 waves * 48 frags * 64 lanes * 4 dwords
// WIB: Wi B-frags (K=32, single K-tile, rows >=17 zero-padded)
//   dword F-OFF = ((w*6 + t)*64 + l)*4 + d ; k = (l>>4)*8 + 2d ; col as above
#define OFF_WIB (OFF_WH + LEN_WH)      // 98304
#define LEN_WIB 12288           // 8 * 6 * 64 * 4
#define OFF_W1 (OFF_WIB + LEN_WIB)     // 110592
#define LEN_W1 68096            // 2 * 133 * 256
#define OFF_W2 (OFF_W1 + LEN_W1)       // 178688
#define LEN_W2 65536            // 2 * 128 * 256
#define OFF_W3 (OFF_W2 + LEN_W2)       // 244224
#define LEN_W3 256              // 2 * 128
#define WS_DWORDS (OFF_W3 + LEN_W3)    // 244480 dwords

__device__ __forceinline__ u32 pack2(float lo, float hi) {
    h2v v; v.x = (_Float16)lo; v.y = (_Float16)hi;
    return __builtin_bit_cast(u32, v);
}

__device__ __forceinline__ float fdot2(u32 a, u32 b, float c) {
#if __has_builtin(__builtin_amdgcn_fdot2)
    return __builtin_amdgcn_fdot2(__builtin_bit_cast(h2v, a),
                                  __builtin_bit_cast(h2v, b), c, false);
#else
    h2v x = __builtin_bit_cast(h2v, a), y = __builtin_bit_cast(h2v, b);
    return c + (float)x.x * (float)y.x + (float)x.y * (float)y.y;
#endif
}

// ---------------- pack kernel ----------------
__global__ __launch_bounds__(256) void pack_kernel(
    const float* __restrict__ Wi, const float* __restrict__ Whrz,
    const float* __restrict__ Whn, const float* __restrict__ W1,
    const float* __restrict__ W2, const float* __restrict__ W3,
    u32* __restrict__ ws)
{
    for (int F = blockIdx.x * 256 + threadIdx.x; F < WS_DWORDS; F += gridDim.x * 256) {
        u32 val;
        if (F < OFF_WIB) {
            int d = F & 3; int r = F >> 2;
            int l = r & 63; int q = r >> 6;      // q = w*48 + f
            int f = q % 48; int w = q / 48;
            int t = f >> 3; int kt = f & 7;
            int g = t >> 1, c = t & 1;
            int k = kt * 32 + ((l >> 4) << 3) + 2 * d;
            int col = g * 256 + w * 32 + c * 16 + (l & 15);
            float lo, hi;
            if (col < 512) { lo = Whrz[k * 512 + col]; hi = Whrz[(k + 1) * 512 + col]; }
            else { lo = Whn[k * 256 + (col - 512)]; hi = Whn[(k + 1) * 256 + (col - 512)]; }
            val = pack2(lo, hi);
        } else if (F < OFF_W1) {
            int j = F - OFF_WIB;
            int d = j & 3; int r = j >> 2;
            int l = r & 63; int q2 = r >> 6;     // q2 = w*6 + t
            int t = q2 % 6; int w = q2 / 6;
            int g = t >> 1, c = t & 1;
            int k = ((l >> 4) << 3) + 2 * d;
            int col = g * 256 + w * 32 + c * 16 + (l & 15);
            float lo = (k < 17) ? Wi[k * 768 + col] : 0.f;
            float hi = (k + 1 < 17) ? Wi[(k + 1) * 768 + col] : 0.f;
            val = pack2(lo, hi);
        } else if (F < OFF_W2) {
            int j = F - OFF_W1; int c = j / (133 * 256); int r = j % (133 * 256);
            int kk = r >> 8; int o = r & 255;
            int k = 2 * kk;
            float lo = W1[(c * 265 + k) * 256 + o];
            float hi = (k + 1 < 265) ? W1[(c * 265 + k + 1) * 256 + o] : 0.f;
            val = pack2(lo, hi);
        } else if (F < OFF_W3) {
            int j = F - OFF_W2; int c = j >> 15; int r = j & 32767;
            int kk = r >> 8; int o = r & 255;
            float lo = W2[(c * 256 + 2 * kk) * 256 + o];
            float hi = W2[(c * 256 + 2 * kk + 1) * 256 + o];
            val = pack2(lo, hi);
        } else {
            int j = F - OFF_W3; int c = j >> 7; int jj = j & 127;
            float lo = W3[c * 256 + 2 * jj];
            float hi = W3[c * 256 + 2 * jj + 1];
            val = pack2(lo, hi);
        }
        ws[F] = val;
    }
}

// ---------------- main kernel: one batch row per workgroup --------------
// Round-2 structure (610us champion) + explicit partial weight residency:
// 32 of 48 Wh B-frags (gates r,z) live in a persistent VGPR array (128
// regs; total demand ~240 <= the 256-reg cap at 2 waves/SIMD), the other
// 16 (gate n) are streamed from L2 each step with loads issued EARLY so
// they hide under the 32 resident-operand MFMAs. Cuts per-step L2 weight
// traffic ~3x (round 2 re-streamed nearly all 48 — VGPR_Count=128 proved
// non-residency and made the step co-bound on L2 feed).
__global__ __launch_bounds__(512, 2) void qnet_kernel(
    const float* __restrict__ particles, const float* __restrict__ pweights,
    const float* __restrict__ actions, const float* __restrict__ timev,
    const float* __restrict__ bi, const float* __restrict__ bn,
    const float* __restrict__ b1, const float* __restrict__ b2,
    const float* __restrict__ b3, const int* __restrict__ nts,
    const u32* __restrict__ ws, float* __restrict__ out)
{
    __shared__ __align__(16) u32 sX[NP * 16];      // 32768 B
    __shared__ __align__(16) float sG[8 * 1536];   // 49152 B
    __shared__ __align__(16) u16 sH2[2][NH];       // 1024 B
    __shared__ __align__(16) float sHf[NH];        // 1024 B
    __shared__ __align__(16) float sMisc[16];      // 64 B

    const int b = blockIdx.x;
    const int tid = threadIdx.x;
    const int lane = tid & 63;
    const int wid = tid >> 6;   // 0..7

    // ---- resident Wh B-frags: tiles 0..3 (r,z gates), 128 VGPRs ----
    f16x8 bres[32];
    {
        const uint4* gp = (const uint4*)(ws + OFF_WH) + (wid * 48) * 64 + lane;
        #pragma unroll
        for (int i = 0; i < 32; ++i) bres[i] = __builtin_bit_cast(f16x8, gp[i * 64]);
    }
    // streamed frags (tiles 4,5 = gate n): re-read from L2 each step
    const uint4* gps = (const uint4*)(ws + OFF_WH) + (wid * 48 + 32) * 64 + lane;

    // ---- stage x rows as fp16 pairs, padded to 16 pairs (K=32 halves) ----
    {
        const float2* pr2 = (const float2*)(particles + (long)b * NP * 16);
        for (int j = tid; j < NP * 8; j += 512) {
            int p = j >> 3, q = j & 7;
            float2 v = pr2[j];
            sX[p * 16 + q] = pack2(v.x, v.y);
        }
        const float* wr = pweights + (long)b * NP;
        for (int j = tid; j < NP * 8; j += 512) {
            int p = j >> 3, q = j & 7;
            sX[p * 16 + 8 + q] = (q == 0) ? pack2(wr[p], 0.f) : 0u;
        }
    }
    if (tid < 256) ((u32*)sH2)[tid] = 0u;
    if (tid < 8) sMisc[tid] = actions[b * 8 + tid];
    if (tid == 8) sMisc[8] = timev[b] / (float)nts[0];

    float birL = 0.f, bizL = 0.f, binnL = 0.f, bnnL = 0.f, hreg = 0.f;
    if (lane < 32) {
        int j = wid * 32 + lane;
        birL = bi[j]; bizL = bi[NH + j]; binnL = bi[2 * NH + j]; bnnL = bn[j];
    }
    __syncthreads();

    const uint4* wibp = (const uint4*)(ws + OFF_WIB) + (wid * 6) * 64 + lane;

    #pragma unroll 1
    for (int p = 0; p < NP; ++p) {
        if ((p & 15) == 0) {
            // ---- x@Wi for steps p..p+15 (intrinsic MFMA, pairwise) ----
            f16x8 av = __builtin_bit_cast(f16x8,
                ((const uint4*)sX)[(p + (lane & 15)) * 4 + (lane >> 4)]);
            f32x4 z4 = {0.f, 0.f, 0.f, 0.f};
            int sb = (lane >> 4) << 2;
            float* gw = sG + wid * 1536 + (lane & 15);
            {
                f32x4 g0 = __builtin_amdgcn_mfma_f32_16x16x32_f16(av, __builtin_bit_cast(f16x8, wibp[0 * 64]), z4, 0, 0, 0);
                f32x4 g1 = __builtin_amdgcn_mfma_f32_16x16x32_f16(av, __builtin_bit_cast(f16x8, wibp[1 * 64]), z4, 0, 0, 0);
                #pragma unroll
                for (int r = 0; r < 4; ++r) {
                    gw[(sb + r) * 32]      = g0[r];
                    gw[(sb + r) * 32 + 16] = g1[r];
                }
            }
            {
                f32x4 g2 = __builtin_amdgcn_mfma_f32_16x16x32_f16(av, __builtin_bit_cast(f16x8, wibp[2 * 64]), z4, 0, 0, 0);
                f32x4 g3 = __builtin_amdgcn_mfma_f32_16x16x32_f16(av, __builtin_bit_cast(f16x8, wibp[3 * 64]), z4, 0, 0, 0);
                #pragma unroll
                for (int r = 0; r < 4; ++r) {
                    gw[512 + (sb + r) * 32]      = g2[r];
                    gw[512 + (sb + r) * 32 + 16] = g3[r];
                }
            }
            {
                f32x4 g4 = __builtin_amdgcn_mfma_f32_16x16x32_f16(av, __builtin_bit_cast(f16x8, wibp[4 * 64]), z4, 0, 0, 0);
                f32x4 g5 = __builtin_amdgcn_mfma_f32_16x16x32_f16(av, __builtin_bit_cast(f16x8, wibp[5 * 64]), z4, 0, 0, 0);
                #pragma unroll
                for (int r = 0; r < 4; ++r) {
                    gw[1024 + (sb + r) * 32]      = g4[r];
                    gw[1024 + (sb + r) * 32 + 16] = g5[r];
                }
            }
            __syncthreads();
        }

        // ---- this step's x@Wi sums (independent of h, read early) ----
        float gR, gZ, gN;
        {
            const float* gp = sG + wid * 1536 + (p & 15) * 32 + (lane & 31);
            gR = gp[0]; gZ = gp[512]; gN = gp[1024];
        }

        const u32* hbuf = (const u32*)(&sH2[p & 1][0]);
        const int hq = lane >> 4;

        // ---- issue gate-n tile-4 stream loads (hide under resident MFMAs) ----
        uint4 s4[8];
        #pragma unroll
        for (int i = 0; i < 8; ++i) s4[i] = gps[i * 64];

        // ---- resident chains: r,z gates (32 MFMAs) ----
        f32x4 a0 = {0.f, 0.f, 0.f, 0.f}, a1 = a0, a2 = a0, a3 = a0;
        #pragma unroll
        for (int kt = 0; kt < 8; ++kt) {
            f16x8 hv = __builtin_bit_cast(f16x8, ((const uint4*)hbuf)[kt * 4 + hq]);
            a0 = __builtin_amdgcn_mfma_f32_16x16x32_f16(hv, bres[kt],      a0, 0, 0, 0);
            a1 = __builtin_amdgcn_mfma_f32_16x16x32_f16(hv, bres[8 + kt],  a1, 0, 0, 0);
            a2 = __builtin_amdgcn_mfma_f32_16x16x32_f16(hv, bres[16 + kt], a2, 0, 0, 0);
            a3 = __builtin_amdgcn_mfma_f32_16x16x32_f16(hv, bres[24 + kt], a3, 0, 0, 0);
        }

        // ---- issue tile-5 loads, then streamed chains (gate n) ----
        uint4 s5[8];
        #pragma unroll
        for (int i = 0; i < 8; ++i) s5[i] = gps[(8 + i) * 64];
        f32x4 a4 = {0.f, 0.f, 0.f, 0.f}, a5 = a4;
        #pragma unroll
        for (int kt = 0; kt < 8; ++kt) {
            f16x8 hv = __builtin_bit_cast(f16x8, ((const uint4*)hbuf)[kt * 4 + hq]);
            a4 = __builtin_amdgcn_mfma_f32_16x16x32_f16(hv, __builtin_bit_cast(f16x8, s4[kt]), a4, 0, 0, 0);
            a5 = __builtin_amdgcn_mfma_f32_16x16x32_f16(hv, __builtin_bit_cast(f16x8, s5[kt]), a5, 0, 0, 0);
        }

        // ---- gates fully in-register (lane l<32 owns h[wid*32+l]) ----
        bool hic = (lane & 16) != 0;
        float srm = hic ? a1[0] : a0[0];
        float szm = hic ? a3[0] : a2[0];
        float snm = hic ? a5[0] : a4[0];
        if (lane < 32) {
            float xr = gR + birL + srm;
            float xz = gZ + bizL + szm;
            float xn = gN + binnL;
            float r = 1.f / (1.f + __expf(-xr));
            float z = 1.f / (1.f + __expf(-xz));
            float targ = xn + r * (snm + bnnL);
            float e2 = __expf(2.f * targ);
            float n = 1.f - 2.f / (e2 + 1.f);
            hreg = (1.f - z) * n + z * hreg;
            _Float16 hh = (_Float16)hreg;
            sH2[(p + 1) & 1][wid * 32 + lane] = __builtin_bit_cast(u16, hh);
        }
        __syncthreads();
    }

    // ---------------- MLP tail ----------------
    if (lane < 32) sHf[wid * 32 + lane] = hreg;
    __syncthreads();
    u32* sHid = (u32*)sG;             // 133 dwords
    u16* sL1 = (u16*)(sG + 512);      // 512 halves
    u16* sL2 = (u16*)(sG + 1024);     // 512 halves
    if (tid < 128) sHid[tid] = pack2(sHf[2 * tid], sHf[2 * tid + 1]);
    else if (tid < 132) { int i = tid - 128; sHid[tid] = pack2(sMisc[2 * i], sMisc[2 * i + 1]); }
    else if (tid == 132) sHid[132] = pack2(sMisc[8], 0.f);
    __syncthreads();
    // L1: 512 outputs (2 critics x 256)
    {
        int c = tid >> 8, o = tid & 255;
        float acc = b1[c * 256 + o];
        const u32* wp = ws + OFF_W1 + c * 133 * 256 + o;
        #pragma unroll 4
        for (int kk = 0; kk < 133; ++kk) acc = fdot2(wp[kk * 256], sHid[kk], acc);
        acc = fmaxf(acc, 0.f);
        _Float16 a16 = (_Float16)acc;
        sL1[tid] = __builtin_bit_cast(u16, a16);
    }
    __syncthreads();
    // L2
    {
        int c = tid >> 8, o = tid & 255;
        float acc = b2[c * 256 + o];
        const u32* wp = ws + OFF_W2 + c * 128 * 256 + o;
        const u32* hp = (const u32*)sL1 + c * 128;
        #pragma unroll 4
        for (int kk = 0; kk < 128; ++kk) acc = fdot2(wp[kk * 256], hp[kk], acc);
        acc = fmaxf(acc, 0.f);
        _Float16 a16 = (_Float16)acc;
        sL2[tid] = __builtin_bit_cast(u16, a16);
    }
    __syncthreads();
    // L3: 2 outputs via wave reduction
    if (tid < 128) {
        int c = tid >> 6, l = tid & 63;
        const u32* wp = ws + OFF_W3 + c * 128;
        const u32* hp = (const u32*)sL2 + c * 128;
        float acc = fdot2(wp[l], hp[l], 0.f);
        acc = fdot2(wp[64 + l], hp[64 + l], acc);
        #pragma unroll
        for (int off = 32; off > 0; off >>= 1) acc += __shfl_down(acc, off);
        if (l == 0) out[b * 2 + c] = acc + b3[c];
    }
}

extern "C" void kernel_launch(void* const* d_in, const int* in_sizes, int n_in,
                              void* d_out, int out_size, void* d_ws, size_t ws_size,
                              hipStream_t stream) {
    const float* particles = (const float*)d_in[0];
    const float* pweights  = (const float*)d_in[1];
    const float* actions   = (const float*)d_in[2];
    const float* timev     = (const float*)d_in[3];
    const float* Wi        = (const float*)d_in[4];
    const float* bi        = (const float*)d_in[5];
    const float* Whrz      = (const float*)d_in[6];
    const float* Whn       = (const float*)d_in[7];
    const float* bn        = (const float*)d_in[8];
    const float* W1        = (const float*)d_in[9];
    const float* b1        = (const float*)d_in[10];
    const float* W2        = (const float*)d_in[11];
    const float* b2        = (const float*)d_in[12];
    const float* W3        = (const float*)d_in[13];
    const float* b3        = (const float*)d_in[14];
    const int*   nts       = (const int*)d_in[15];
    u32* ws = (u32*)d_ws;
    float* outp = (float*)d_out;

    pack_kernel<<<(WS_DWORDS + 255) / 256, 256, 0, stream>>>(Wi, Whrz, Whn, W1, W2, W3, ws);
    qnet_kernel<<<NB, 512, 0, stream>>>(particles, pweights, actions, timev,
                                        bi, bn, b1, b2, b3, nts, ws, outp);
}

// Round 12
// 666.183 us; speedup vs baseline: 1.2186x; 1.2186x over previous
//
#include <hip/hip_runtime.h>
#include <hip/hip_fp16.h>

typedef _Float16 h2v __attribute__((ext_vector_type(2)));
typedef _Float16 f16x8 __attribute__((ext_vector_type(8)));
typedef float f32x4 __attribute__((ext_vector_type(4)));
typedef unsigned int u32;
typedef unsigned short u16;

#define NB 256
#define NP 512
#define NH 256

// ws layout in dwords (identical to rounds 2..11)
// WH: Wh B-frags. dword F = (((w*48 + f)*64 + l)*4 + d)
//   f = t*8 + kt; t = g*2 + c (g=gate 0..2, c=col-half 0..1), kt = K-tile 0..7
//   k = kt*32 + (l>>4)*8 + 2d (+1 for hi half), col = g*256 + w*32 + c*16 + (l&15)
#define OFF_WH 0
#define LEN_WH 98304            // 8 waves * 48 frags * 64 lanes * 4 dwords
// WIB: Wi B-frags (K=32, single K-tile, rows >=17 zero-padded)
#define OFF_WIB (OFF_WH + LEN_WH)      // 98304
#define LEN_WIB 12288           // 8 * 6 * 64 * 4
#define OFF_W1 (OFF_WIB + LEN_WIB)     // 110592
#define LEN_W1 68096            // 2 * 133 * 256
#define OFF_W2 (OFF_W1 + LEN_W1)       // 178688
#define LEN_W2 65536            // 2 * 128 * 256
#define OFF_W3 (OFF_W2 + LEN_W2)       // 244224
#define LEN_W3 256              // 2 * 128
#define WS_DWORDS (OFF_W3 + LEN_W3)    // 244480 dwords

__device__ __forceinline__ u32 pack2(float lo, float hi) {
    h2v v; v.x = (_Float16)lo; v.y = (_Float16)hi;
    return __builtin_bit_cast(u32, v);
}

__device__ __forceinline__ float fdot2(u32 a, u32 b, float c) {
#if __has_builtin(__builtin_amdgcn_fdot2)
    return __builtin_amdgcn_fdot2(__builtin_bit_cast(h2v, a),
                                  __builtin_bit_cast(h2v, b), c, false);
#else
    h2v x = __builtin_bit_cast(h2v, a), y = __builtin_bit_cast(h2v, b);
    return c + (float)x.x * (float)y.x + (float)x.y * (float)y.y;
#endif
}

// ---------------- pack kernel ----------------
__global__ __launch_bounds__(256) void pack_kernel(
    const float* __restrict__ Wi, const float* __restrict__ Whrz,
    const float* __restrict__ Whn, const float* __restrict__ W1,
    const float* __restrict__ W2, const float* __restrict__ W3,
    u32* __restrict__ ws)
{
    for (int F = blockIdx.x * 256 + threadIdx.x; F < WS_DWORDS; F += gridDim.x * 256) {
        u32 val;
        if (F < OFF_WIB) {
            int d = F & 3; int r = F >> 2;
            int l = r & 63; int q = r >> 6;      // q = w*48 + f
            int f = q % 48; int w = q / 48;
            int t = f >> 3; int kt = f & 7;
            int g = t >> 1, c = t & 1;
            int k = kt * 32 + ((l >> 4) << 3) + 2 * d;
            int col = g * 256 + w * 32 + c * 16 + (l & 15);
            float lo, hi;
            if (col < 512) { lo = Whrz[k * 512 + col]; hi = Whrz[(k + 1) * 512 + col]; }
            else { lo = Whn[k * 256 + (col - 512)]; hi = Whn[(k + 1) * 256 + (col - 512)]; }
            val = pack2(lo, hi);
        } else if (F < OFF_W1) {
            int j = F - OFF_WIB;
            int d = j & 3; int r = j >> 2;
            int l = r & 63; int q2 = r >> 6;     // q2 = w*6 + t
            int t = q2 % 6; int w = q2 / 6;
            int g = t >> 1, c = t & 1;
            int k = ((l >> 4) << 3) + 2 * d;
            int col = g * 256 + w * 32 + c * 16 + (l & 15);
            float lo = (k < 17) ? Wi[k * 768 + col] : 0.f;
            float hi = (k + 1 < 17) ? Wi[(k + 1) * 768 + col] : 0.f;
            val = pack2(lo, hi);
        } else if (F < OFF_W2) {
            int j = F - OFF_W1; int c = j / (133 * 256); int r = j % (133 * 256);
            int kk = r >> 8; int o = r & 255;
            int k = 2 * kk;
            float lo = W1[(c * 265 + k) * 256 + o];
            float hi = (k + 1 < 265) ? W1[(c * 265 + k + 1) * 256 + o] : 0.f;
            val = pack2(lo, hi);
        } else if (F < OFF_W3) {
            int j = F - OFF_W2; int c = j >> 15; int r = j & 32767;
            int kk = r >> 8; int o = r & 255;
            float lo = W2[(c * 256 + 2 * kk) * 256 + o];
            float hi = W2[(c * 256 + 2 * kk + 1) * 256 + o];
            val = pack2(lo, hi);
        } else {
            int j = F - OFF_W3; int c = j >> 7; int jj = j & 127;
            float lo = W3[c * 256 + 2 * jj];
            float hi = W3[c * 256 + 2 * jj + 1];
            val = pack2(lo, hi);
        }
        ws[F] = val;
    }
}

// ---------------- main kernel: one batch row per workgroup --------------
// Round 2 is L2-BW-bound: 393KB/step of Wh B-frags re-streamed from L2 =
// 2913 cyc at 135 B/cyc/CU ~= the whole measured 2860-cyc step. Fix: split
// the weight feed across TWO parallel pipes. Gate-n's 16 frags (131KB)
// live in LDS (loaded once); gates r,z (262KB/step) stream from L2 via
// direct pointer reads (no arrays -> no spill: rounds 3/4/6/10/11 proved
// explicit residency always spills or gets the accvgpr tax). L2 1940cyc
// and LDS ~1200cyc overlap -> step ~2000cyc. To fit 160KB LDS, the x@Wi
// chunk buffer is fp16 and x is staged per-16-step chunk with reg prefetch.
__global__ __launch_bounds__(512, 2) void qnet_kernel(
    const float* __restrict__ particles, const float* __restrict__ pweights,
    const float* __restrict__ actions, const float* __restrict__ timev,
    const float* __restrict__ bi, const float* __restrict__ bn,
    const float* __restrict__ b1, const float* __restrict__ b2,
    const float* __restrict__ b3, const int* __restrict__ nts,
    const u32* __restrict__ ws, float* __restrict__ out)
{
    __shared__ __align__(16) u32 sWn[32768];     // 131072 B: gate-n frags [w][16][64][4]
    __shared__ __align__(16) u16 sGh[8 * 1536];  // 24576 B: x@Wi chunk, fp16
    __shared__ __align__(16) u32 sXc[256];       // 1024 B: x chunk (16 steps x 16 dw)
    __shared__ __align__(16) u16 sH2[2][NH];     // 1024 B
    __shared__ __align__(16) float sHf[NH];      // 1024 B
    __shared__ __align__(16) float sMisc[16];    // 64 B
    // total 158784 B < 163840

    const int b = blockIdx.x;
    const int tid = threadIdx.x;
    const int lane = tid & 63;
    const int wid = tid >> 6;   // 0..7

    // ---- gate-n Wh frags (tiles 4,5) -> LDS, once ----
    // sWn[j], j = (w*16 + i)*256 + l*4 + d  <->  ws[OFF_WH + j + (w+1)*8192]
    for (int j = tid; j < 32768; j += 512)
        sWn[j] = ws[OFF_WH + j + ((j >> 12) + 1) * 8192];

    if (tid < 256) ((u32*)sH2)[tid] = 0u;
    if (tid < 8) sMisc[tid] = actions[b * 8 + tid];
    if (tid == 8) sMisc[8] = timev[b] / (float)nts[0];

    float birL = 0.f, bizL = 0.f, binnL = 0.f, bnnL = 0.f, hreg = 0.f;
    if (lane < 32) {
        int j = wid * 32 + lane;
        birL = bi[j]; bizL = bi[NH + j]; binnL = bi[2 * NH + j]; bnnL = bn[j];
    }

    // ---- x chunk prefetch roles (tid<256): step=tid>>4, dword=tid&15 ----
    const int xs = tid >> 4;
    const int xd = tid & 15;
    float2 pv = {0.f, 0.f}; float wv = 0.f;
    if (tid < 256) {
        if (xd < 8) pv = *(const float2*)(particles + ((long)b * NP + xs) * 16 + 2 * xd);
        else if (xd == 8) wv = pweights[(long)b * NP + xs];
    }
    __syncthreads();

    const uint4* wibp = (const uint4*)(ws + OFF_WIB) + (wid * 6) * 64 + lane;
    const uint4* gpr = (const uint4*)(ws + OFF_WH) + (wid * 48) * 64 + lane;  // streamed r,z
    const uint4* wn  = ((const uint4*)sWn) + (wid * 16) * 64 + lane;          // LDS n
    const int hq = lane >> 4;

    #pragma unroll 1
    for (int p = 0; p < NP; ++p) {
        if ((p & 15) == 0) {
            // ---- commit prefetched x chunk to LDS ----
            if (tid < 256) {
                u32 v;
                if (xd < 8) v = pack2(pv.x, pv.y);
                else if (xd == 8) v = pack2(wv, 0.f);
                else v = 0u;
                sXc[xs * 16 + xd] = v;
            }
            __syncthreads();
            // ---- x@Wi for steps p..p+15 (rows = steps, K=32) ----
            f16x8 av = __builtin_bit_cast(f16x8,
                ((const uint4*)sXc)[(lane & 15) * 4 + (lane >> 4)]);
            f32x4 z4 = {0.f, 0.f, 0.f, 0.f};
            int sb = (lane >> 4) << 2;
            int c16 = lane & 15;
            u16* gw = sGh + wid * 1536;
            {
                f32x4 g0 = __builtin_amdgcn_mfma_f32_16x16x32_f16(av, __builtin_bit_cast(f16x8, wibp[0 * 64]), z4, 0, 0, 0);
                f32x4 g1 = __builtin_amdgcn_mfma_f32_16x16x32_f16(av, __builtin_bit_cast(f16x8, wibp[1 * 64]), z4, 0, 0, 0);
                #pragma unroll
                for (int r = 0; r < 4; ++r) {
                    gw[(sb + r) * 32 + c16]      = __builtin_bit_cast(u16, (_Float16)g0[r]);
                    gw[(sb + r) * 32 + c16 + 16] = __builtin_bit_cast(u16, (_Float16)g1[r]);
                }
            }
            {
                f32x4 g2 = __builtin_amdgcn_mfma_f32_16x16x32_f16(av, __builtin_bit_cast(f16x8, wibp[2 * 64]), z4, 0, 0, 0);
                f32x4 g3 = __builtin_amdgcn_mfma_f32_16x16x32_f16(av, __builtin_bit_cast(f16x8, wibp[3 * 64]), z4, 0, 0, 0);
                #pragma unroll
                for (int r = 0; r < 4; ++r) {
                    gw[512 + (sb + r) * 32 + c16]      = __builtin_bit_cast(u16, (_Float16)g2[r]);
                    gw[512 + (sb + r) * 32 + c16 + 16] = __builtin_bit_cast(u16, (_Float16)g3[r]);
                }
            }
            {
                f32x4 g4 = __builtin_amdgcn_mfma_f32_16x16x32_f16(av, __builtin_bit_cast(f16x8, wibp[4 * 64]), z4, 0, 0, 0);
                f32x4 g5 = __builtin_amdgcn_mfma_f32_16x16x32_f16(av, __builtin_bit_cast(f16x8, wibp[5 * 64]), z4, 0, 0, 0);
                #pragma unroll
                for (int r = 0; r < 4; ++r) {
                    gw[1024 + (sb + r) * 32 + c16]      = __builtin_bit_cast(u16, (_Float16)g4[r]);
                    gw[1024 + (sb + r) * 32 + c16 + 16] = __builtin_bit_cast(u16, (_Float16)g5[r]);
                }
            }
            // ---- prefetch next chunk (hides under the next 16 steps) ----
            if (tid < 256 && p + 16 < NP) {
                int ps = p + 16 + xs;
                if (xd < 8) pv = *(const float2*)(particles + ((long)b * NP + ps) * 16 + 2 * xd);
                else if (xd == 8) wv = pweights[(long)b * NP + ps];
            }
            __syncthreads();
        }

        // ---- this step's x@Wi sums (fp16 -> f32) ----
        float gR, gZ, gN;
        {
            const u16* gp = sGh + wid * 1536 + (p & 15) * 32 + (lane & 31);
            gR = (float)__builtin_bit_cast(_Float16, gp[0]);
            gZ = (float)__builtin_bit_cast(_Float16, gp[512]);
            gN = (float)__builtin_bit_cast(_Float16, gp[1024]);
        }

        // ---- h@Wh: r,z streamed from L2; n from LDS (parallel pipes) ----
        const u32* hbuf = (const u32*)(&sH2[p & 1][0]);
        f32x4 a0 = {0.f, 0.f, 0.f, 0.f}, a1 = a0, a2 = a0, a3 = a0, a4 = a0, a5 = a0;
        #pragma unroll
        for (int kt = 0; kt < 8; ++kt) {
            f16x8 hv = __builtin_bit_cast(f16x8, ((const uint4*)hbuf)[kt * 4 + hq]);
            a0 = __builtin_amdgcn_mfma_f32_16x16x32_f16(hv, __builtin_bit_cast(f16x8, gpr[kt * 64]),        a0, 0, 0, 0);
            a1 = __builtin_amdgcn_mfma_f32_16x16x32_f16(hv, __builtin_bit_cast(f16x8, gpr[(8 + kt) * 64]),  a1, 0, 0, 0);
            a2 = __builtin_amdgcn_mfma_f32_16x16x32_f16(hv, __builtin_bit_cast(f16x8, gpr[(16 + kt) * 64]), a2, 0, 0, 0);
            a3 = __builtin_amdgcn_mfma_f32_16x16x32_f16(hv, __builtin_bit_cast(f16x8, gpr[(24 + kt) * 64]), a3, 0, 0, 0);
            a4 = __builtin_amdgcn_mfma_f32_16x16x32_f16(hv, __builtin_bit_cast(f16x8, wn[kt * 64]),         a4, 0, 0, 0);
            a5 = __builtin_amdgcn_mfma_f32_16x16x32_f16(hv, __builtin_bit_cast(f16x8, wn[(8 + kt) * 64]),   a5, 0, 0, 0);
        }

        // ---- gates fully in-register (lane l<32 owns h[wid*32+l]) ----
        bool hic = (lane & 16) != 0;
        float srm = hic ? a1[0] : a0[0];
        float szm = hic ? a3[0] : a2[0];
        float snm = hic ? a5[0] : a4[0];
        if (lane < 32) {
            float xr = gR + birL + srm;
            float xz = gZ + bizL + szm;
            float xn = gN + binnL;
            float r = 1.f / (1.f + __expf(-xr));
            float z = 1.f / (1.f + __expf(-xz));
            float targ = xn + r * (snm + bnnL);
            float e2 = __expf(2.f * targ);
            float n = 1.f - 2.f / (e2 + 1.f);
            hreg = (1.f - z) * n + z * hreg;
            _Float16 hh = (_Float16)hreg;
            sH2[(p + 1) & 1][wid * 32 + lane] = __builtin_bit_cast(u16, hh);
        }
        __syncthreads();
    }

    // ---------------- MLP tail (overlays scan-dead sWn) ----------------
    if (lane < 32) sHf[wid * 32 + lane] = hreg;
    __syncthreads();
    u32* sHid = sWn;                  // 133 dwords
    u16* sL1 = (u16*)(sWn + 256);     // 512 halves
    u16* sL2 = (u16*)(sWn + 640);     // 512 halves
    if (tid < 128) sHid[tid] = pack2(sHf[2 * tid], sHf[2 * tid + 1]);
    else if (tid < 132) { int i = tid - 128; sHid[tid] = pack2(sMisc[2 * i], sMisc[2 * i + 1]); }
    else if (tid == 132) sHid[132] = pack2(sMisc[8], 0.f);
    __syncthreads();
    // L1: 512 outputs (2 critics x 256)
    {
        int c = tid >> 8, o = tid & 255;
        float acc = b1[c * 256 + o];
        const u32* wp = ws + OFF_W1 + c * 133 * 256 + o;
        #pragma unroll 4
        for (int kk = 0; kk < 133; ++kk) acc = fdot2(wp[kk * 256], sHid[kk], acc);
        acc = fmaxf(acc, 0.f);
        _Float16 a16 = (_Float16)acc;
        sL1[tid] = __builtin_bit_cast(u16, a16);
    }
    __syncthreads();
    // L2
    {
        int c = tid >> 8, o = tid & 255;
        float acc = b2[c * 256 + o];
        const u32* wp = ws + OFF_W2 + c * 128 * 256 + o;
        const u32* hp = (const u32*)sL1 + c * 128;
        #pragma unroll 4
        for (int kk = 0; kk < 128; ++kk) acc = fdot2(wp[kk * 256], hp[kk], acc);
        acc = fmaxf(acc, 0.f);
        _Float16 a16 = (_Float16)acc;
        sL2[tid] = __builtin_bit_cast(u16, a16);
    }
    __syncthreads();
    // L3: 2 outputs via wave reduction
    if (tid < 128) {
        int c = tid >> 6, l = tid & 63;
        const u32* wp = ws + OFF_W3 + c * 128;
        const u32* hp = (const u32*)sL2 + c * 128;
        float acc = fdot2(wp[l], hp[l], 0.f);
        acc = fdot2(wp[64 + l], hp[64 + l], acc);
        #pragma unroll
        for (int off = 32; off > 0; off >>= 1) acc += __shfl_down(acc, off);
        if (l == 0) out[b * 2 + c] = acc + b3[c];
    }
}

extern "C" void kernel_launch(void* const* d_in, const int* in_sizes, int n_in,
                              void* d_out, int out_size, void* d_ws, size_t ws_size,
                              hipStream_t stream) {
    const float* particles = (const float*)d_in[0];
    const float* pweights  = (const float*)d_in[1];
    const float* actions   = (const float*)d_in[2];
    const float* timev     = (const float*)d_in[3];
    const float* Wi        = (const float*)d_in[4];
    const float* bi        = (const float*)d_in[5];
    const float* Whrz      = (const float*)d_in[6];
    const float* Whn       = (const float*)d_in[7];
    const float* bn        = (const float*)d_in[8];
    const float* W1        = (const float*)d_in[9];
    const float* b1        = (const float*)d_in[10];
    const float* W2        = (const float*)d_in[11];
    const float* b2        = (const float*)d_in[12];
    const float* W3        = (const float*)d_in[13];
    const float* b3        = (const float*)d_in[14];
    const int*   nts       = (const int*)d_in[15];
    u32* ws = (u32*)d_ws;
    float* outp = (float*)d_out;

    pack_kernel<<<(WS_DWORDS + 255) / 256, 256, 0, stream>>>(Wi, Whrz, Whn, W1, W2, W3, ws);
    qnet_kernel<<<NB, 512, 0, stream>>>(particles, pweights, actions, timev,
                                        bi, bn, b1, b2, b3, nts, ws, outp);
}